// Round 1
// baseline (392.434 us; speedup 1.0000x reference)
//
#include <hip/hip_runtime.h>

// SelMaxPool via fixed-capacity destination-cluster bins (no scan):
//   A) memset: count[M] + overflow cursor = 0
//   B) bin_scatter: pos=atomicAdd(count[m]); pos<CAP -> records[m*CAP+pos]=src,
//      else overflow list (expected ~0-20 entries for Poisson(14.2) @ CAP=64).
//      m = dst >> log2(pool) (cluster is i//pool by construction; array fallback).
//   C) gather: one wave per cluster. Bin loaded ONCE into registers
//      (lane-held, shfl-broadcast), pad lanes with member row index so
//      redundant max contributions are free. 4x-unrolled batch: 16 rows /
//      4 independent float4 loads in flight per lane before one waitcnt
//      (latency-bound fix: was 2 loads/epoch). Member rows fused into the
//      same epoch. Overflow entries handled inline (fixup kernel removed).
//      shfl_xor cross-reduce, 256B nontemporal store.
// Fallback (ws too small): check-then-atomicMax path.
// C fixed at 64 by the reference (16 float4 chunks per row).

#define NEG_FLT_MAX (-3.402823466e38f)
#define OFL_CAP 8192

typedef float fvec4 __attribute__((ext_vector_type(4)));

__device__ __forceinline__ float4 fmax4(float4 a, float4 b) {
    return make_float4(fmaxf(a.x, b.x), fmaxf(a.y, b.y),
                       fmaxf(a.z, b.z), fmaxf(a.w, b.w));
}

// ---------------- binned path ----------------

__global__ void bin_scatter_kernel(const int* __restrict__ edge_index,
                                   const int* __restrict__ selections,
                                   const int* __restrict__ cluster,
                                   const int* __restrict__ ksz,
                                   unsigned* __restrict__ count,
                                   unsigned* __restrict__ records,
                                   unsigned* __restrict__ ofl,   // [0]=cursor, pairs after
                                   int E, int cap, int shift) {
    int e = blockIdx.x * blockDim.x + threadIdx.x;
    if (e >= E) return;
    int ks = ksz[0];
    // streamed-once data: nontemporal loads keep LLC free for x (gather)
    int sel = __builtin_nontemporal_load(&selections[e]);
    if (sel >= ks * ks) return;
    int dst = __builtin_nontemporal_load(&edge_index[E + e]);
    int m = (shift >= 0) ? (dst >> shift) : cluster[dst];
    unsigned src = (unsigned)__builtin_nontemporal_load(&edge_index[e]);
    unsigned pos = atomicAdd(&count[m], 1u);
    if (pos < (unsigned)cap) {
        __builtin_nontemporal_store(src, &records[(size_t)m * cap + pos]);
    } else {
        unsigned idx = atomicAdd(&ofl[0], 1u);
        if (idx < OFL_CAP) { ofl[1 + 2 * idx] = (unsigned)m; ofl[2 + 2 * idx] = src; }
    }
}

__global__ __launch_bounds__(256) void gather_kernel(
        const float* __restrict__ x,
        const unsigned* __restrict__ records,
        const unsigned* __restrict__ count,
        const unsigned* __restrict__ ofl,
        float* __restrict__ out, int M, int pool, int cap) {
    int lane = threadIdx.x & 63;
    int wave = threadIdx.x >> 6;
    int m = blockIdx.x * 4 + wave;
    if (m >= M) return;
    int r  = lane >> 4;                        // row slot 0..3
    int c4 = lane & 15;                        // float4 chunk within row
    const float4* x4 = (const float4*)x;
    unsigned mbase = (unsigned)(m * pool);

    // load bin once; pad unused lanes with first member row (harmless for max)
    unsigned cnt_raw = count[m];
    int cnt_c = min((int)cnt_raw, cap);
    unsigned rec = mbase;
    if (lane < cnt_c)
        rec = __builtin_nontemporal_load(&records[(size_t)m * cap + lane]);

    float4 acc = make_float4(NEG_FLT_MAX, NEG_FLT_MAX, NEG_FLT_MAX, NEG_FLT_MAX);

    // member rows (cluster = contiguous blocks of `pool` nodes); for pool=4
    // this is one load per lane, issued alongside the first record batch below
    for (int k = r; k < pool; k += 4)
        acc = fmax4(acc, x4[((size_t)mbase + k) * 16 + c4]);

    // binned rows: 16 rows per batch, 4 independent loads in flight per lane
    for (int base = 0; base < cnt_c; base += 16) {
        unsigned s0 = (unsigned)__shfl((int)rec, base + r,      64);
        unsigned s1 = (unsigned)__shfl((int)rec, base + 4 + r,  64);
        unsigned s2 = (unsigned)__shfl((int)rec, base + 8 + r,  64);
        unsigned s3 = (unsigned)__shfl((int)rec, base + 12 + r, 64);
        float4 v0 = x4[(size_t)s0 * 16 + c4];
        float4 v1 = x4[(size_t)s1 * 16 + c4];
        float4 v2 = x4[(size_t)s2 * 16 + c4];
        float4 v3 = x4[(size_t)s3 * 16 + c4];
        acc = fmax4(acc, fmax4(fmax4(v0, v1), fmax4(v2, v3)));
    }

    // rare overflow (count > cap): this wave scans the global overflow list
    // (expected ~0-20 entries total) -- replaces the separate fixup kernel
    if ((int)cnt_raw > cap) {
        unsigned n = ofl[0];
        if (n > OFL_CAP) n = OFL_CAP;
        for (unsigned i = 0; i < n; ++i) {
            unsigned mi = ofl[1 + 2 * i];
            if (mi == (unsigned)m) {
                unsigned si = ofl[2 + 2 * i];
                acc = fmax4(acc, x4[(size_t)si * 16 + c4]);
            }
        }
    }

    // reduce across the 4 row-slot groups
    for (int off = 16; off < 64; off <<= 1) {
        acc.x = fmaxf(acc.x, __shfl_xor(acc.x, off, 64));
        acc.y = fmaxf(acc.y, __shfl_xor(acc.y, off, 64));
        acc.z = fmaxf(acc.z, __shfl_xor(acc.z, off, 64));
        acc.w = fmaxf(acc.w, __shfl_xor(acc.w, off, 64));
    }
    if (r == 0) {
        fvec4 o = { acc.x, acc.y, acc.z, acc.w };
        __builtin_nontemporal_store(o, (fvec4*)&((float4*)out)[(size_t)m * 16 + c4]);
    }
}

// ---------------- fallback path (no workspace) ----------------

__device__ __forceinline__ unsigned enc_f(float f) {
    unsigned b = __float_as_uint(f);
    return (b & 0x80000000u) ? ~b : (b | 0x80000000u);
}
__device__ __forceinline__ float dec_f(unsigned u) {
    unsigned b = (u & 0x80000000u) ? (u & 0x7fffffffu) : ~u;
    return __uint_as_float(b);
}

__global__ void pool_init_kernel(const float* __restrict__ x,
                                 unsigned* __restrict__ out_u, int M, int pool) {
    int idx = blockIdx.x * blockDim.x + threadIdx.x;
    if (idx >= M * 16) return;
    int m = idx >> 4, c4 = idx & 15;
    const float4* x4 = (const float4*)x;
    size_t base = (size_t)m * pool;
    float4 v = x4[base * 16 + c4];
    for (int k = 1; k < pool; ++k) v = fmax4(v, x4[(base + k) * 16 + c4]);
    uint4 u; u.x = enc_f(v.x); u.y = enc_f(v.y); u.z = enc_f(v.z); u.w = enc_f(v.w);
    ((uint4*)out_u)[idx] = u;
}

__global__ void edge_scatter_kernel(const float* __restrict__ x,
                                    const int* __restrict__ edge_index,
                                    const int* __restrict__ selections,
                                    const int* __restrict__ cluster,
                                    const int* __restrict__ ksz,
                                    unsigned* __restrict__ out_u, int E) {
    int t = blockIdx.x * blockDim.x + threadIdx.x;
    int e = t >> 4;
    if (e >= E) return;
    int c4 = t & 15;
    int ks = ksz[0];
    if (selections[e] >= ks * ks) return;
    int src = edge_index[e];
    int m = cluster[edge_index[E + e]];
    float4 v = ((const float4*)x)[(size_t)src * 16 + c4];
    unsigned e0 = enc_f(v.x), e1 = enc_f(v.y), e2 = enc_f(v.z), e3 = enc_f(v.w);
    unsigned* o = out_u + (size_t)m * 64 + c4 * 4;
    uint4 cur = *(const uint4*)o;
    if (e0 > cur.x) atomicMax(o + 0, e0);
    if (e1 > cur.y) atomicMax(o + 1, e1);
    if (e2 > cur.z) atomicMax(o + 2, e2);
    if (e3 > cur.w) atomicMax(o + 3, e3);
}

__global__ void decode_kernel(unsigned* __restrict__ out_u, int total4) {
    int idx = blockIdx.x * blockDim.x + threadIdx.x;
    if (idx >= total4) return;
    uint4 u = ((uint4*)out_u)[idx];
    float4 f; f.x = dec_f(u.x); f.y = dec_f(u.y); f.z = dec_f(u.z); f.w = dec_f(u.w);
    ((float4*)out_u)[idx] = f;
}

// ---------------- launch ----------------

extern "C" void kernel_launch(void* const* d_in, const int* in_sizes, int n_in,
                              void* d_out, int out_size, void* d_ws, size_t ws_size,
                              hipStream_t stream) {
    const float* x          = (const float*)d_in[0];
    const int*   edge_index = (const int*)d_in[1];
    const int*   selections = (const int*)d_in[2];
    const int*   cluster    = (const int*)d_in[3];
    const int*   ksz        = (const int*)d_in[4];

    const int C = 64;
    int N = in_sizes[0] / C;
    int E = in_sizes[1] / 2;
    int M = out_size / C;
    int pool = N / M;                          // 4

    int shift = -1;
    if (pool > 0 && (pool & (pool - 1)) == 0) {
        shift = 0;
        while ((1 << shift) < pool) ++shift;
    }

    // workspace layout (unsigned words): count[M] | ofl cursor+pairs | records
    size_t off_count   = 0;
    size_t off_ofl     = off_count + (size_t)M;            // 64B-aligned (M mult of 16)
    size_t off_records = (off_ofl + 1 + 2 * (size_t)OFL_CAP + 15) & ~(size_t)15;
    size_t fixed_bytes = off_records * 4;

    int cap = 0;
    if (ws_size > fixed_bytes)
        cap = (int)((ws_size - fixed_bytes) / ((size_t)M * 4));
    if (cap > 64) cap = 64;

    if (cap >= 16) {
        unsigned* ws      = (unsigned*)d_ws;
        unsigned* count   = ws + off_count;
        unsigned* ofl     = ws + off_ofl;
        unsigned* records = ws + off_records;
        float*    out     = (float*)d_out;

        // zero counts + overflow cursor (contiguous)
        hipMemsetAsync(count, 0, (size_t)M * 4 + 4, stream);

        bin_scatter_kernel<<<(E + 255) / 256, 256, 0, stream>>>(
            edge_index, selections, cluster, ksz, count, records, ofl,
            E, cap, shift);
        gather_kernel<<<(M + 3) / 4, 256, 0, stream>>>(
            x, records, count, ofl, out, M, pool, cap);
    } else {
        // fallback: no-workspace atomicMax path
        unsigned* out_u = (unsigned*)d_out;
        int t1 = M * 16;
        pool_init_kernel<<<(t1 + 255) / 256, 256, 0, stream>>>(x, out_u, M, pool);
        long long t2 = (long long)E * 16;
        edge_scatter_kernel<<<(int)((t2 + 255) / 256), 256, 0, stream>>>(
            x, edge_index, selections, cluster, ksz, out_u, E);
        decode_kernel<<<(t1 + 255) / 256, 256, 0, stream>>>(out_u, t1);
    }
}